// Round 1
// baseline (1236.165 us; speedup 1.0000x reference)
//
#include <hip/hip_runtime.h>
#include <math.h>

#define N_NODES 100000
#define N_EDGES 1600000
#define DIM_IN  256
#define DIM_H   64
#define DIM_C   47

// ---------- degree / normalization ----------
__global__ __launch_bounds__(256) void k_init_deg(float* __restrict__ deg) {
  int i = blockIdx.x * 256 + threadIdx.x;
  if (i < N_NODES) deg[i] = 1.0f;  // self-loop
}

__global__ __launch_bounds__(256) void k_count_deg(const int* __restrict__ dst,
                                                   float* __restrict__ deg) {
  int e = blockIdx.x * 256 + threadIdx.x;
  if (e < N_EDGES) atomicAdd(&deg[dst[e]], 1.0f);
}

__global__ __launch_bounds__(256) void k_dinv(float* __restrict__ deg) {
  int i = blockIdx.x * 256 + threadIdx.x;
  if (i < N_NODES) deg[i] = rsqrtf(deg[i]);
}

// ---------- layer 1 GEMM: h1 = x @ W1  (wave per row, lane = out column) ----------
__global__ __launch_bounds__(256) void k_gemm1(const float* __restrict__ x,
                                               const float* __restrict__ W,
                                               float* __restrict__ h1) {
  int row = blockIdx.x * 4 + (threadIdx.x >> 6);
  int j   = threadIdx.x & 63;
  if (row >= N_NODES) return;
  const float* xr = x + (size_t)row * DIM_IN;
  float acc = 0.0f;
#pragma unroll 8
  for (int k = 0; k < DIM_IN; ++k)
    acc += xr[k] * W[k * DIM_H + j];
  h1[(size_t)row * DIM_H + j] = acc;
}

// ---------- agg1 init: self-loop + bias ----------
__global__ __launch_bounds__(256) void k_init_agg1(const float* __restrict__ h1,
                                                   const float* __restrict__ dinv,
                                                   const float* __restrict__ b1,
                                                   float* __restrict__ agg1) {
  int row = blockIdx.x * 4 + (threadIdx.x >> 6);
  int j   = threadIdx.x & 63;
  if (row >= N_NODES) return;
  float di = dinv[row];
  agg1[(size_t)row * DIM_H + j] = di * di * h1[(size_t)row * DIM_H + j] + b1[j];
}

// ---------- agg1 edge scatter: wave per edge, lane per channel ----------
__global__ __launch_bounds__(256) void k_edge_agg1(const int* __restrict__ src,
                                                   const int* __restrict__ dst,
                                                   const float* __restrict__ dinv,
                                                   const float* __restrict__ h1,
                                                   float* __restrict__ agg1) {
  int e = blockIdx.x * 4 + (threadIdx.x >> 6);
  int j = threadIdx.x & 63;
  if (e >= N_EDGES) return;
  int s = src[e], d = dst[e];
  float w = dinv[s] * dinv[d];
  atomicAdd(&agg1[(size_t)d * DIM_H + j], w * h1[(size_t)s * DIM_H + j]);
}

// ---------- layer 2 GEMM with fused ReLU on input: h2 = relu(agg1) @ W2 ----------
__global__ __launch_bounds__(256) void k_gemm2(const float* __restrict__ agg1,
                                               const float* __restrict__ W,
                                               float* __restrict__ h2) {
  int row = blockIdx.x * 4 + (threadIdx.x >> 6);
  int j   = threadIdx.x & 63;
  if (row >= N_NODES) return;
  const float* hr = agg1 + (size_t)row * DIM_H;
  float acc = 0.0f;
  if (j < DIM_C) {
#pragma unroll 8
    for (int k = 0; k < DIM_H; ++k)
      acc += fmaxf(hr[k], 0.0f) * W[k * DIM_C + j];
    h2[(size_t)row * DIM_C + j] = acc;
  }
}

// ---------- agg2 init into d_out ----------
__global__ __launch_bounds__(256) void k_init_agg2(const float* __restrict__ h2,
                                                   const float* __restrict__ dinv,
                                                   const float* __restrict__ b2,
                                                   float* __restrict__ out) {
  int row = blockIdx.x * 4 + (threadIdx.x >> 6);
  int j   = threadIdx.x & 63;
  if (row >= N_NODES || j >= DIM_C) return;
  float di = dinv[row];
  out[(size_t)row * DIM_C + j] = di * di * h2[(size_t)row * DIM_C + j] + b2[j];
}

// ---------- agg2 edge scatter ----------
__global__ __launch_bounds__(256) void k_edge_agg2(const int* __restrict__ src,
                                                   const int* __restrict__ dst,
                                                   const float* __restrict__ dinv,
                                                   const float* __restrict__ h2,
                                                   float* __restrict__ out) {
  int e = blockIdx.x * 4 + (threadIdx.x >> 6);
  int j = threadIdx.x & 63;
  if (e >= N_EDGES || j >= DIM_C) return;
  int s = src[e], d = dst[e];
  float w = dinv[s] * dinv[d];
  atomicAdd(&out[(size_t)d * DIM_C + j], w * h2[(size_t)s * DIM_C + j]);
}

// ---------- log_softmax in place (wave per row) ----------
__global__ __launch_bounds__(256) void k_log_softmax(float* __restrict__ out) {
  int row = blockIdx.x * 4 + (threadIdx.x >> 6);
  int j   = threadIdx.x & 63;
  if (row >= N_NODES) return;
  float v = (j < DIM_C) ? out[(size_t)row * DIM_C + j] : -INFINITY;
  float m = v;
  for (int o = 32; o; o >>= 1) m = fmaxf(m, __shfl_xor(m, o));
  float ex = (j < DIM_C) ? __expf(v - m) : 0.0f;
  float s = ex;
  for (int o = 32; o; o >>= 1) s += __shfl_xor(s, o);
  if (j < DIM_C) out[(size_t)row * DIM_C + j] = v - m - __logf(s);
}

extern "C" void kernel_launch(void* const* d_in, const int* in_sizes, int n_in,
                              void* d_out, int out_size, void* d_ws, size_t ws_size,
                              hipStream_t stream) {
  const float* x  = (const float*)d_in[0];
  const float* W1 = (const float*)d_in[1];
  const float* b1 = (const float*)d_in[2];
  const float* W2 = (const float*)d_in[3];
  const float* b2 = (const float*)d_in[4];
  const int*   ei = (const int*)d_in[5];
  const int* src = ei;
  const int* dst = ei + N_EDGES;
  float* out = (float*)d_out;

  float* ws   = (float*)d_ws;
  float* dinv = ws;                                   // N
  float* h1   = dinv + N_NODES;                       // N*64
  float* agg1 = h1 + (size_t)N_NODES * DIM_H;         // N*64
  float* h2   = agg1 + (size_t)N_NODES * DIM_H;       // N*47

  const int nblk_n  = (N_NODES + 255) / 256;          // thread-per-node kernels
  const int nblk_e  = (N_EDGES + 255) / 256;          // thread-per-edge kernels
  const int nblk_nw = (N_NODES + 3) / 4;              // wave-per-node kernels
  const int nblk_ew = (N_EDGES + 3) / 4;              // wave-per-edge kernels

  k_init_deg<<<nblk_n, 256, 0, stream>>>(dinv);
  k_count_deg<<<nblk_e, 256, 0, stream>>>(dst, dinv);
  k_dinv<<<nblk_n, 256, 0, stream>>>(dinv);

  k_gemm1<<<nblk_nw, 256, 0, stream>>>(x, W1, h1);
  k_init_agg1<<<nblk_nw, 256, 0, stream>>>(h1, dinv, b1, agg1);
  k_edge_agg1<<<nblk_ew, 256, 0, stream>>>(src, dst, dinv, h1, agg1);

  k_gemm2<<<nblk_nw, 256, 0, stream>>>(agg1, W2, h2);
  k_init_agg2<<<nblk_nw, 256, 0, stream>>>(h2, dinv, b2, out);
  k_edge_agg2<<<nblk_ew, 256, 0, stream>>>(src, dst, dinv, h2, out);

  k_log_softmax<<<nblk_nw, 256, 0, stream>>>(out);
}

// Round 2
// 1069.453 us; speedup vs baseline: 1.1559x; 1.1559x over previous
//
#include <hip/hip_runtime.h>
#include <math.h>

#define N_NODES 100000
#define N_EDGES 1600000
#define DIM_IN  256
#define DIM_H   64
#define DIM_C   47

// ---------- degree / normalization ----------
__global__ __launch_bounds__(256) void k_init_deg(float* __restrict__ deg) {
  int i = blockIdx.x * 256 + threadIdx.x;
  if (i < N_NODES) deg[i] = 1.0f;  // self-loop
}

__global__ __launch_bounds__(256) void k_count_deg(const int* __restrict__ dst,
                                                   float* __restrict__ deg) {
  int e = blockIdx.x * 256 + threadIdx.x;
  if (e < N_EDGES) atomicAdd(&deg[dst[e]], 1.0f);
}

__global__ __launch_bounds__(256) void k_dinv(float* __restrict__ deg) {
  int i = blockIdx.x * 256 + threadIdx.x;
  if (i < N_NODES) deg[i] = rsqrtf(deg[i]);
}

// ---------- layer 1 GEMM: h1 = x @ W1 ----------
// Block = 256 threads (4 waves), 64 rows/block. W1 staged in LDS transposed+padded.
// Each thread: lane j = output col, 4 concurrent row-accumulators (ILP),
// ds_read_b128 of Wt[j][k..k+3] reused across the 4 rows.
__global__ __launch_bounds__(256) void k_gemm1(const float* __restrict__ x,
                                               const float* __restrict__ W,
                                               float* __restrict__ h1) {
  __shared__ float Wt[DIM_H][DIM_IN + 4];  // transposed, +4 pad -> bank (4j+k)%32
  for (int i = threadIdx.x; i < DIM_IN * DIM_H; i += 256) {
    int k = i >> 6, j = i & 63;
    Wt[j][k] = W[i];
  }
  __syncthreads();

  const int j    = threadIdx.x & 63;
  const int wave = threadIdx.x >> 6;
  const int base = blockIdx.x * 64 + wave * 16;

  for (int rr = 0; rr < 16; rr += 4) {
    const int r0 = base + rr;
    const int c0 = (r0 + 0 < N_NODES) ? r0 + 0 : N_NODES - 1;
    const int c1 = (r0 + 1 < N_NODES) ? r0 + 1 : N_NODES - 1;
    const int c2 = (r0 + 2 < N_NODES) ? r0 + 2 : N_NODES - 1;
    const int c3 = (r0 + 3 < N_NODES) ? r0 + 3 : N_NODES - 1;
    const float* x0 = x + (size_t)c0 * DIM_IN;
    const float* x1 = x + (size_t)c1 * DIM_IN;
    const float* x2 = x + (size_t)c2 * DIM_IN;
    const float* x3 = x + (size_t)c3 * DIM_IN;
    float acc0 = 0.f, acc1 = 0.f, acc2 = 0.f, acc3 = 0.f;
#pragma unroll 2
    for (int k = 0; k < DIM_IN; k += 4) {
      float4 w  = *(const float4*)&Wt[j][k];
      float4 a0 = *(const float4*)(x0 + k);
      float4 a1 = *(const float4*)(x1 + k);
      float4 a2 = *(const float4*)(x2 + k);
      float4 a3 = *(const float4*)(x3 + k);
      acc0 = fmaf(a0.x, w.x, acc0); acc0 = fmaf(a0.y, w.y, acc0);
      acc0 = fmaf(a0.z, w.z, acc0); acc0 = fmaf(a0.w, w.w, acc0);
      acc1 = fmaf(a1.x, w.x, acc1); acc1 = fmaf(a1.y, w.y, acc1);
      acc1 = fmaf(a1.z, w.z, acc1); acc1 = fmaf(a1.w, w.w, acc1);
      acc2 = fmaf(a2.x, w.x, acc2); acc2 = fmaf(a2.y, w.y, acc2);
      acc2 = fmaf(a2.z, w.z, acc2); acc2 = fmaf(a2.w, w.w, acc2);
      acc3 = fmaf(a3.x, w.x, acc3); acc3 = fmaf(a3.y, w.y, acc3);
      acc3 = fmaf(a3.z, w.z, acc3); acc3 = fmaf(a3.w, w.w, acc3);
    }
    if (r0 + 0 < N_NODES) h1[(size_t)(r0 + 0) * DIM_H + j] = acc0;
    if (r0 + 1 < N_NODES) h1[(size_t)(r0 + 1) * DIM_H + j] = acc1;
    if (r0 + 2 < N_NODES) h1[(size_t)(r0 + 2) * DIM_H + j] = acc2;
    if (r0 + 3 < N_NODES) h1[(size_t)(r0 + 3) * DIM_H + j] = acc3;
  }
}

// ---------- agg1 init: self-loop + bias ----------
__global__ __launch_bounds__(256) void k_init_agg1(const float* __restrict__ h1,
                                                   const float* __restrict__ dinv,
                                                   const float* __restrict__ b1,
                                                   float* __restrict__ agg1) {
  int row = blockIdx.x * 4 + (threadIdx.x >> 6);
  int j   = threadIdx.x & 63;
  if (row >= N_NODES) return;
  float di = dinv[row];
  agg1[(size_t)row * DIM_H + j] = di * di * h1[(size_t)row * DIM_H + j] + b1[j];
}

// ---------- agg1 edge scatter: wave per edge, lane per channel ----------
__global__ __launch_bounds__(256) void k_edge_agg1(const int* __restrict__ src,
                                                   const int* __restrict__ dst,
                                                   const float* __restrict__ dinv,
                                                   const float* __restrict__ h1,
                                                   float* __restrict__ agg1) {
  int e = blockIdx.x * 4 + (threadIdx.x >> 6);
  int j = threadIdx.x & 63;
  if (e >= N_EDGES) return;
  int s = src[e], d = dst[e];
  float w = dinv[s] * dinv[d];
  atomicAdd(&agg1[(size_t)d * DIM_H + j], w * h1[(size_t)s * DIM_H + j]);
}

// ---------- layer 2 GEMM with fused ReLU: h2 = relu(agg1) @ W2 ----------
__global__ __launch_bounds__(256) void k_gemm2(const float* __restrict__ agg1,
                                               const float* __restrict__ W,
                                               float* __restrict__ h2) {
  __shared__ float Wt[DIM_C][DIM_H + 4];  // transposed, +4 pad
  for (int i = threadIdx.x; i < DIM_H * DIM_C; i += 256) {
    int k = i / DIM_C, j = i % DIM_C;
    Wt[j][k] = W[i];
  }
  __syncthreads();

  const int j    = threadIdx.x & 63;
  const int wave = threadIdx.x >> 6;
  const int base = blockIdx.x * 64 + wave * 16;

  if (j < DIM_C) {
    for (int rr = 0; rr < 16; rr += 4) {
      const int r0 = base + rr;
      const int c0 = (r0 + 0 < N_NODES) ? r0 + 0 : N_NODES - 1;
      const int c1 = (r0 + 1 < N_NODES) ? r0 + 1 : N_NODES - 1;
      const int c2 = (r0 + 2 < N_NODES) ? r0 + 2 : N_NODES - 1;
      const int c3 = (r0 + 3 < N_NODES) ? r0 + 3 : N_NODES - 1;
      const float* x0 = agg1 + (size_t)c0 * DIM_H;
      const float* x1 = agg1 + (size_t)c1 * DIM_H;
      const float* x2 = agg1 + (size_t)c2 * DIM_H;
      const float* x3 = agg1 + (size_t)c3 * DIM_H;
      float acc0 = 0.f, acc1 = 0.f, acc2 = 0.f, acc3 = 0.f;
#pragma unroll 2
      for (int k = 0; k < DIM_H; k += 4) {
        float4 w  = *(const float4*)&Wt[j][k];
        float4 a0 = *(const float4*)(x0 + k);
        float4 a1 = *(const float4*)(x1 + k);
        float4 a2 = *(const float4*)(x2 + k);
        float4 a3 = *(const float4*)(x3 + k);
        a0.x = fmaxf(a0.x, 0.f); a0.y = fmaxf(a0.y, 0.f); a0.z = fmaxf(a0.z, 0.f); a0.w = fmaxf(a0.w, 0.f);
        a1.x = fmaxf(a1.x, 0.f); a1.y = fmaxf(a1.y, 0.f); a1.z = fmaxf(a1.z, 0.f); a1.w = fmaxf(a1.w, 0.f);
        a2.x = fmaxf(a2.x, 0.f); a2.y = fmaxf(a2.y, 0.f); a2.z = fmaxf(a2.z, 0.f); a2.w = fmaxf(a2.w, 0.f);
        a3.x = fmaxf(a3.x, 0.f); a3.y = fmaxf(a3.y, 0.f); a3.z = fmaxf(a3.z, 0.f); a3.w = fmaxf(a3.w, 0.f);
        acc0 = fmaf(a0.x, w.x, acc0); acc0 = fmaf(a0.y, w.y, acc0);
        acc0 = fmaf(a0.z, w.z, acc0); acc0 = fmaf(a0.w, w.w, acc0);
        acc1 = fmaf(a1.x, w.x, acc1); acc1 = fmaf(a1.y, w.y, acc1);
        acc1 = fmaf(a1.z, w.z, acc1); acc1 = fmaf(a1.w, w.w, acc1);
        acc2 = fmaf(a2.x, w.x, acc2); acc2 = fmaf(a2.y, w.y, acc2);
        acc2 = fmaf(a2.z, w.z, acc2); acc2 = fmaf(a2.w, w.w, acc2);
        acc3 = fmaf(a3.x, w.x, acc3); acc3 = fmaf(a3.y, w.y, acc3);
        acc3 = fmaf(a3.z, w.z, acc3); acc3 = fmaf(a3.w, w.w, acc3);
      }
      if (r0 + 0 < N_NODES) h2[(size_t)(r0 + 0) * DIM_C + j] = acc0;
      if (r0 + 1 < N_NODES) h2[(size_t)(r0 + 1) * DIM_C + j] = acc1;
      if (r0 + 2 < N_NODES) h2[(size_t)(r0 + 2) * DIM_C + j] = acc2;
      if (r0 + 3 < N_NODES) h2[(size_t)(r0 + 3) * DIM_C + j] = acc3;
    }
  }
}

// ---------- agg2 init into d_out ----------
__global__ __launch_bounds__(256) void k_init_agg2(const float* __restrict__ h2,
                                                   const float* __restrict__ dinv,
                                                   const float* __restrict__ b2,
                                                   float* __restrict__ out) {
  int row = blockIdx.x * 4 + (threadIdx.x >> 6);
  int j   = threadIdx.x & 63;
  if (row >= N_NODES || j >= DIM_C) return;
  float di = dinv[row];
  out[(size_t)row * DIM_C + j] = di * di * h2[(size_t)row * DIM_C + j] + b2[j];
}

// ---------- agg2 edge scatter ----------
__global__ __launch_bounds__(256) void k_edge_agg2(const int* __restrict__ src,
                                                   const int* __restrict__ dst,
                                                   const float* __restrict__ dinv,
                                                   const float* __restrict__ h2,
                                                   float* __restrict__ out) {
  int e = blockIdx.x * 4 + (threadIdx.x >> 6);
  int j = threadIdx.x & 63;
  if (e >= N_EDGES || j >= DIM_C) return;
  int s = src[e], d = dst[e];
  float w = dinv[s] * dinv[d];
  atomicAdd(&out[(size_t)d * DIM_C + j], w * h2[(size_t)s * DIM_C + j]);
}

// ---------- log_softmax in place (wave per row) ----------
__global__ __launch_bounds__(256) void k_log_softmax(float* __restrict__ out) {
  int row = blockIdx.x * 4 + (threadIdx.x >> 6);
  int j   = threadIdx.x & 63;
  if (row >= N_NODES) return;
  float v = (j < DIM_C) ? out[(size_t)row * DIM_C + j] : -INFINITY;
  float m = v;
  for (int o = 32; o; o >>= 1) m = fmaxf(m, __shfl_xor(m, o));
  float ex = (j < DIM_C) ? __expf(v - m) : 0.0f;
  float s = ex;
  for (int o = 32; o; o >>= 1) s += __shfl_xor(s, o);
  if (j < DIM_C) out[(size_t)row * DIM_C + j] = v - m - __logf(s);
}

extern "C" void kernel_launch(void* const* d_in, const int* in_sizes, int n_in,
                              void* d_out, int out_size, void* d_ws, size_t ws_size,
                              hipStream_t stream) {
  const float* x  = (const float*)d_in[0];
  const float* W1 = (const float*)d_in[1];
  const float* b1 = (const float*)d_in[2];
  const float* W2 = (const float*)d_in[3];
  const float* b2 = (const float*)d_in[4];
  const int*   ei = (const int*)d_in[5];
  const int* src = ei;
  const int* dst = ei + N_EDGES;
  float* out = (float*)d_out;

  float* ws   = (float*)d_ws;
  float* dinv = ws;                                   // N
  float* h1   = dinv + N_NODES;                       // N*64
  float* agg1 = h1 + (size_t)N_NODES * DIM_H;         // N*64
  float* h2   = agg1 + (size_t)N_NODES * DIM_H;       // N*47

  const int nblk_n  = (N_NODES + 255) / 256;
  const int nblk_e  = (N_EDGES + 255) / 256;
  const int nblk_nw = (N_NODES + 3) / 4;              // wave-per-node kernels
  const int nblk_ew = (N_EDGES + 3) / 4;              // wave-per-edge kernels
  const int nblk_g  = (N_NODES + 63) / 64;            // tiled GEMMs

  k_init_deg<<<nblk_n, 256, 0, stream>>>(dinv);
  k_count_deg<<<nblk_e, 256, 0, stream>>>(dst, dinv);
  k_dinv<<<nblk_n, 256, 0, stream>>>(dinv);

  k_gemm1<<<nblk_g, 256, 0, stream>>>(x, W1, h1);
  k_init_agg1<<<nblk_nw, 256, 0, stream>>>(h1, dinv, b1, agg1);
  k_edge_agg1<<<nblk_ew, 256, 0, stream>>>(src, dst, dinv, h1, agg1);

  k_gemm2<<<nblk_g, 256, 0, stream>>>(agg1, W2, h2);
  k_init_agg2<<<nblk_nw, 256, 0, stream>>>(h2, dinv, b2, out);
  k_edge_agg2<<<nblk_ew, 256, 0, stream>>>(src, dst, dinv, h2, out);

  k_log_softmax<<<nblk_nw, 256, 0, stream>>>(out);
}

// Round 3
// 762.640 us; speedup vs baseline: 1.6209x; 1.4023x over previous
//
#include <hip/hip_runtime.h>
#include <math.h>

#define N_NODES 100000
#define N_EDGES 1600000
#define DIM_IN  256
#define DIM_H   64
#define DIM_C   47
#define SCAN_CHUNK 1024                      // elems per scan block (256 thr x 4)
#define NBLK_SCAN ((N_NODES + SCAN_CHUNK - 1) / SCAN_CHUNK)   // 98

// ---------- zero int buffers (cnt, cursor) ----------
__global__ __launch_bounds__(256) void k_zero(int* __restrict__ cnt,
                                              int* __restrict__ cursor) {
  int i = blockIdx.x * 256 + threadIdx.x;
  if (i < N_NODES) { cnt[i] = 0; cursor[i] = 0; }
}

// ---------- in-degree histogram ----------
__global__ __launch_bounds__(256) void k_hist(const int* __restrict__ dst,
                                              int* __restrict__ cnt) {
  int e = blockIdx.x * 256 + threadIdx.x;
  if (e < N_EDGES) atomicAdd(&cnt[dst[e]], 1);
}

// ---------- dinv = rsqrt(deg+1)  (self-loop) ----------
__global__ __launch_bounds__(256) void k_dinv(const int* __restrict__ cnt,
                                              float* __restrict__ dinv) {
  int i = blockIdx.x * 256 + threadIdx.x;
  if (i < N_NODES) dinv[i] = rsqrtf((float)cnt[i] + 1.0f);
}

// ---------- exclusive scan of cnt -> row_start (3 kernels) ----------
__global__ __launch_bounds__(256) void k_scan_partial(const int* __restrict__ cnt,
                                                      int* __restrict__ row_start,
                                                      int* __restrict__ blk_sums) {
  __shared__ int ls[256];
  const int tid  = threadIdx.x;
  const int base = blockIdx.x * SCAN_CHUNK + tid * 4;
  int c0 = (base + 0 < N_NODES) ? cnt[base + 0] : 0;
  int c1 = (base + 1 < N_NODES) ? cnt[base + 1] : 0;
  int c2 = (base + 2 < N_NODES) ? cnt[base + 2] : 0;
  int c3 = (base + 3 < N_NODES) ? cnt[base + 3] : 0;
  int tsum = c0 + c1 + c2 + c3;
  ls[tid] = tsum;
  __syncthreads();
  for (int off = 1; off < 256; off <<= 1) {
    int v = (tid >= off) ? ls[tid - off] : 0;
    __syncthreads();
    ls[tid] += v;
    __syncthreads();
  }
  int excl = ls[tid] - tsum;
  if (base + 0 < N_NODES) row_start[base + 0] = excl;
  if (base + 1 < N_NODES) row_start[base + 1] = excl + c0;
  if (base + 2 < N_NODES) row_start[base + 2] = excl + c0 + c1;
  if (base + 3 < N_NODES) row_start[base + 3] = excl + c0 + c1 + c2;
  if (tid == 255) blk_sums[blockIdx.x] = ls[255];
}

__global__ __launch_bounds__(128) void k_scan_blk(int* __restrict__ blk_sums) {
  __shared__ int ls[128];
  const int tid = threadIdx.x;
  int v = (tid < NBLK_SCAN) ? blk_sums[tid] : 0;
  ls[tid] = v;
  __syncthreads();
  for (int off = 1; off < 128; off <<= 1) {
    int u = (tid >= off) ? ls[tid - off] : 0;
    __syncthreads();
    ls[tid] += u;
    __syncthreads();
  }
  if (tid < NBLK_SCAN) blk_sums[tid] = ls[tid] - v;
}

__global__ __launch_bounds__(256) void k_scan_add(int* __restrict__ row_start,
                                                  const int* __restrict__ blk_sums) {
  int i = blockIdx.x * 256 + threadIdx.x;
  if (i < N_NODES) row_start[i] += blk_sums[i / SCAN_CHUNK];
}

// ---------- scatter src ids into dst-sorted order ----------
__global__ __launch_bounds__(256) void k_scatter(const int* __restrict__ src,
                                                 const int* __restrict__ dst,
                                                 const int* __restrict__ row_start,
                                                 int* __restrict__ cursor,
                                                 int* __restrict__ sorted_src) {
  int e = blockIdx.x * 256 + threadIdx.x;
  if (e >= N_EDGES) return;
  int d = dst[e];
  int pos = row_start[d] + atomicAdd(&cursor[d], 1);
  sorted_src[pos] = src[e];
}

// ---------- layer 1 GEMM: h1 = x @ W1 (LDS-staged W, 4-row ILP) ----------
__global__ __launch_bounds__(256) void k_gemm1(const float* __restrict__ x,
                                               const float* __restrict__ W,
                                               float* __restrict__ h1) {
  __shared__ float Wt[DIM_H][DIM_IN + 4];
  for (int i = threadIdx.x; i < DIM_IN * DIM_H; i += 256) {
    int k = i >> 6, j = i & 63;
    Wt[j][k] = W[i];
  }
  __syncthreads();

  const int j    = threadIdx.x & 63;
  const int wave = threadIdx.x >> 6;
  const int base = blockIdx.x * 64 + wave * 16;

  for (int rr = 0; rr < 16; rr += 4) {
    const int r0 = base + rr;
    const int c0 = (r0 + 0 < N_NODES) ? r0 + 0 : N_NODES - 1;
    const int c1 = (r0 + 1 < N_NODES) ? r0 + 1 : N_NODES - 1;
    const int c2 = (r0 + 2 < N_NODES) ? r0 + 2 : N_NODES - 1;
    const int c3 = (r0 + 3 < N_NODES) ? r0 + 3 : N_NODES - 1;
    const float* x0 = x + (size_t)c0 * DIM_IN;
    const float* x1 = x + (size_t)c1 * DIM_IN;
    const float* x2 = x + (size_t)c2 * DIM_IN;
    const float* x3 = x + (size_t)c3 * DIM_IN;
    float acc0 = 0.f, acc1 = 0.f, acc2 = 0.f, acc3 = 0.f;
#pragma unroll 2
    for (int k = 0; k < DIM_IN; k += 4) {
      float4 w  = *(const float4*)&Wt[j][k];
      float4 a0 = *(const float4*)(x0 + k);
      float4 a1 = *(const float4*)(x1 + k);
      float4 a2 = *(const float4*)(x2 + k);
      float4 a3 = *(const float4*)(x3 + k);
      acc0 = fmaf(a0.x, w.x, acc0); acc0 = fmaf(a0.y, w.y, acc0);
      acc0 = fmaf(a0.z, w.z, acc0); acc0 = fmaf(a0.w, w.w, acc0);
      acc1 = fmaf(a1.x, w.x, acc1); acc1 = fmaf(a1.y, w.y, acc1);
      acc1 = fmaf(a1.z, w.z, acc1); acc1 = fmaf(a1.w, w.w, acc1);
      acc2 = fmaf(a2.x, w.x, acc2); acc2 = fmaf(a2.y, w.y, acc2);
      acc2 = fmaf(a2.z, w.z, acc2); acc2 = fmaf(a2.w, w.w, acc2);
      acc3 = fmaf(a3.x, w.x, acc3); acc3 = fmaf(a3.y, w.y, acc3);
      acc3 = fmaf(a3.z, w.z, acc3); acc3 = fmaf(a3.w, w.w, acc3);
    }
    if (r0 + 0 < N_NODES) h1[(size_t)(r0 + 0) * DIM_H + j] = acc0;
    if (r0 + 1 < N_NODES) h1[(size_t)(r0 + 1) * DIM_H + j] = acc1;
    if (r0 + 2 < N_NODES) h1[(size_t)(r0 + 2) * DIM_H + j] = acc2;
    if (r0 + 3 < N_NODES) h1[(size_t)(r0 + 3) * DIM_H + j] = acc3;
  }
}

// ---------- agg1 gather: wave per node, lane = channel, CSR loop ----------
// agg1[n][j] = dinv[n]^2*h1[n][j] + b1[j] + sum_e dinv[s]*dinv[n]*h1[s][j]
__global__ __launch_bounds__(256) void k_agg1_gather(const float* __restrict__ h1,
                                                     const float* __restrict__ dinv,
                                                     const float* __restrict__ b1,
                                                     const int* __restrict__ row_start,
                                                     const int* __restrict__ cnt,
                                                     const int* __restrict__ sorted_src,
                                                     float* __restrict__ agg1) {
  int n = blockIdx.x * 4 + (threadIdx.x >> 6);
  int j = threadIdx.x & 63;
  if (n >= N_NODES) return;
  float di = dinv[n];
  float acc = di * di * h1[(size_t)n * DIM_H + j] + b1[j];
  int start = row_start[n];
  int deg   = cnt[n];
  for (int k = 0; k < deg; ++k) {
    int s = sorted_src[start + k];
    float w = dinv[s] * di;
    acc = fmaf(w, h1[(size_t)s * DIM_H + j], acc);
  }
  agg1[(size_t)n * DIM_H + j] = acc;
}

// ---------- layer 2 GEMM with fused ReLU: h2 = relu(agg1) @ W2 ----------
__global__ __launch_bounds__(256) void k_gemm2(const float* __restrict__ agg1,
                                               const float* __restrict__ W,
                                               float* __restrict__ h2) {
  __shared__ float Wt[DIM_C][DIM_H + 4];
  for (int i = threadIdx.x; i < DIM_H * DIM_C; i += 256) {
    int k = i / DIM_C, j = i % DIM_C;
    Wt[j][k] = W[i];
  }
  __syncthreads();

  const int j    = threadIdx.x & 63;
  const int wave = threadIdx.x >> 6;
  const int base = blockIdx.x * 64 + wave * 16;

  if (j < DIM_C) {
    for (int rr = 0; rr < 16; rr += 4) {
      const int r0 = base + rr;
      const int c0 = (r0 + 0 < N_NODES) ? r0 + 0 : N_NODES - 1;
      const int c1 = (r0 + 1 < N_NODES) ? r0 + 1 : N_NODES - 1;
      const int c2 = (r0 + 2 < N_NODES) ? r0 + 2 : N_NODES - 1;
      const int c3 = (r0 + 3 < N_NODES) ? r0 + 3 : N_NODES - 1;
      const float* x0 = agg1 + (size_t)c0 * DIM_H;
      const float* x1 = agg1 + (size_t)c1 * DIM_H;
      const float* x2 = agg1 + (size_t)c2 * DIM_H;
      const float* x3 = agg1 + (size_t)c3 * DIM_H;
      float acc0 = 0.f, acc1 = 0.f, acc2 = 0.f, acc3 = 0.f;
#pragma unroll 2
      for (int k = 0; k < DIM_H; k += 4) {
        float4 w  = *(const float4*)&Wt[j][k];
        float4 a0 = *(const float4*)(x0 + k);
        float4 a1 = *(const float4*)(x1 + k);
        float4 a2 = *(const float4*)(x2 + k);
        float4 a3 = *(const float4*)(x3 + k);
        a0.x = fmaxf(a0.x, 0.f); a0.y = fmaxf(a0.y, 0.f); a0.z = fmaxf(a0.z, 0.f); a0.w = fmaxf(a0.w, 0.f);
        a1.x = fmaxf(a1.x, 0.f); a1.y = fmaxf(a1.y, 0.f); a1.z = fmaxf(a1.z, 0.f); a1.w = fmaxf(a1.w, 0.f);
        a2.x = fmaxf(a2.x, 0.f); a2.y = fmaxf(a2.y, 0.f); a2.z = fmaxf(a2.z, 0.f); a2.w = fmaxf(a2.w, 0.f);
        a3.x = fmaxf(a3.x, 0.f); a3.y = fmaxf(a3.y, 0.f); a3.z = fmaxf(a3.z, 0.f); a3.w = fmaxf(a3.w, 0.f);
        acc0 = fmaf(a0.x, w.x, acc0); acc0 = fmaf(a0.y, w.y, acc0);
        acc0 = fmaf(a0.z, w.z, acc0); acc0 = fmaf(a0.w, w.w, acc0);
        acc1 = fmaf(a1.x, w.x, acc1); acc1 = fmaf(a1.y, w.y, acc1);
        acc1 = fmaf(a1.z, w.z, acc1); acc1 = fmaf(a1.w, w.w, acc1);
        acc2 = fmaf(a2.x, w.x, acc2); acc2 = fmaf(a2.y, w.y, acc2);
        acc2 = fmaf(a2.z, w.z, acc2); acc2 = fmaf(a2.w, w.w, acc2);
        acc3 = fmaf(a3.x, w.x, acc3); acc3 = fmaf(a3.y, w.y, acc3);
        acc3 = fmaf(a3.z, w.z, acc3); acc3 = fmaf(a3.w, w.w, acc3);
      }
      if (r0 + 0 < N_NODES) h2[(size_t)(r0 + 0) * DIM_C + j] = acc0;
      if (r0 + 1 < N_NODES) h2[(size_t)(r0 + 1) * DIM_C + j] = acc1;
      if (r0 + 2 < N_NODES) h2[(size_t)(r0 + 2) * DIM_C + j] = acc2;
      if (r0 + 3 < N_NODES) h2[(size_t)(r0 + 3) * DIM_C + j] = acc3;
    }
  }
}

// ---------- agg2 gather + fused log_softmax: wave per node ----------
__global__ __launch_bounds__(256) void k_agg2_gather(const float* __restrict__ h2,
                                                     const float* __restrict__ dinv,
                                                     const float* __restrict__ b2,
                                                     const int* __restrict__ row_start,
                                                     const int* __restrict__ cnt,
                                                     const int* __restrict__ sorted_src,
                                                     float* __restrict__ out) {
  int n = blockIdx.x * 4 + (threadIdx.x >> 6);
  int j = threadIdx.x & 63;
  if (n >= N_NODES) return;
  int jj = (j < DIM_C) ? j : (DIM_C - 1);  // clamp; lanes >=47 compute junk, masked later
  float di = dinv[n];
  float acc = di * di * h2[(size_t)n * DIM_C + jj] + b2[jj];
  int start = row_start[n];
  int deg   = cnt[n];
  for (int k = 0; k < deg; ++k) {
    int s = sorted_src[start + k];
    float w = dinv[s] * di;
    acc = fmaf(w, h2[(size_t)s * DIM_C + jj], acc);
  }
  // fused log_softmax over the 47 classes
  float v = (j < DIM_C) ? acc : -INFINITY;
  float m = v;
  for (int o = 32; o; o >>= 1) m = fmaxf(m, __shfl_xor(m, o));
  float ex = (j < DIM_C) ? __expf(v - m) : 0.0f;
  float s = ex;
  for (int o = 32; o; o >>= 1) s += __shfl_xor(s, o);
  if (j < DIM_C) out[(size_t)n * DIM_C + j] = v - m - __logf(s);
}

extern "C" void kernel_launch(void* const* d_in, const int* in_sizes, int n_in,
                              void* d_out, int out_size, void* d_ws, size_t ws_size,
                              hipStream_t stream) {
  const float* x  = (const float*)d_in[0];
  const float* W1 = (const float*)d_in[1];
  const float* b1 = (const float*)d_in[2];
  const float* W2 = (const float*)d_in[3];
  const float* b2 = (const float*)d_in[4];
  const int*   ei = (const int*)d_in[5];
  const int* src = ei;
  const int* dst = ei + N_EDGES;
  float* out = (float*)d_out;

  // workspace layout (floats then ints), ~59 MB total
  float* ws   = (float*)d_ws;
  float* dinv = ws;                                   // N
  float* h1   = dinv + N_NODES;                       // N*64 (reused for h2)
  float* agg1 = h1 + (size_t)N_NODES * DIM_H;         // N*64
  float* h2   = h1;                                   // alias: h1 dead after agg1
  int* ibuf       = (int*)(agg1 + (size_t)N_NODES * DIM_H);
  int* cnt        = ibuf;                             // N
  int* cursor     = cnt + N_NODES;                    // N
  int* row_start  = cursor + N_NODES;                 // N
  int* blk_sums   = row_start + N_NODES;              // 128
  int* sorted_src = blk_sums + 128;                   // E

  const int nblk_n  = (N_NODES + 255) / 256;
  const int nblk_e  = (N_EDGES + 255) / 256;
  const int nblk_nw = (N_NODES + 3) / 4;              // wave-per-node kernels
  const int nblk_g  = (N_NODES + 63) / 64;            // tiled GEMMs

  // CSR build
  k_zero<<<nblk_n, 256, 0, stream>>>(cnt, cursor);
  k_hist<<<nblk_e, 256, 0, stream>>>(dst, cnt);
  k_dinv<<<nblk_n, 256, 0, stream>>>(cnt, dinv);
  k_scan_partial<<<NBLK_SCAN, 256, 0, stream>>>(cnt, row_start, blk_sums);
  k_scan_blk<<<1, 128, 0, stream>>>(blk_sums);
  k_scan_add<<<nblk_n, 256, 0, stream>>>(row_start, blk_sums);
  k_scatter<<<nblk_e, 256, 0, stream>>>(src, dst, row_start, cursor, sorted_src);

  // layer 1
  k_gemm1<<<nblk_g, 256, 0, stream>>>(x, W1, h1);
  k_agg1_gather<<<nblk_nw, 256, 0, stream>>>(h1, dinv, b1, row_start, cnt, sorted_src, agg1);

  // layer 2 (+ fused log_softmax)
  k_gemm2<<<nblk_g, 256, 0, stream>>>(agg1, W2, h2);
  k_agg2_gather<<<nblk_nw, 256, 0, stream>>>(h2, dinv, b2, row_start, cnt, sorted_src, out);
}

// Round 4
// 608.254 us; speedup vs baseline: 2.0323x; 1.2538x over previous
//
#include <hip/hip_runtime.h>
#include <math.h>

#define N_NODES 100000
#define N_EDGES 1600000
#define DIM_IN  256
#define DIM_H   64
#define DIM_C   47
#define SCAN_CHUNK 1024                      // elems per scan block (256 thr x 4)
#define NBLK_SCAN ((N_NODES + SCAN_CHUNK - 1) / SCAN_CHUNK)   // 98

// ---------- zero int buffers (cnt, cursor) ----------
__global__ __launch_bounds__(256) void k_zero(int* __restrict__ cnt,
                                              int* __restrict__ cursor) {
  int i = blockIdx.x * 256 + threadIdx.x;
  if (i < N_NODES) { cnt[i] = 0; cursor[i] = 0; }
}

// ---------- in-degree histogram ----------
__global__ __launch_bounds__(256) void k_hist(const int* __restrict__ dst,
                                              int* __restrict__ cnt) {
  int e = blockIdx.x * 256 + threadIdx.x;
  if (e < N_EDGES) atomicAdd(&cnt[dst[e]], 1);
}

// ---------- dinv = rsqrt(deg+1)  (self-loop) ----------
__global__ __launch_bounds__(256) void k_dinv(const int* __restrict__ cnt,
                                              float* __restrict__ dinv) {
  int i = blockIdx.x * 256 + threadIdx.x;
  if (i < N_NODES) dinv[i] = rsqrtf((float)cnt[i] + 1.0f);
}

// ---------- exclusive scan of cnt -> row_start (3 kernels) ----------
__global__ __launch_bounds__(256) void k_scan_partial(const int* __restrict__ cnt,
                                                      int* __restrict__ row_start,
                                                      int* __restrict__ blk_sums) {
  __shared__ int ls[256];
  const int tid  = threadIdx.x;
  const int base = blockIdx.x * SCAN_CHUNK + tid * 4;
  int c0 = (base + 0 < N_NODES) ? cnt[base + 0] : 0;
  int c1 = (base + 1 < N_NODES) ? cnt[base + 1] : 0;
  int c2 = (base + 2 < N_NODES) ? cnt[base + 2] : 0;
  int c3 = (base + 3 < N_NODES) ? cnt[base + 3] : 0;
  int tsum = c0 + c1 + c2 + c3;
  ls[tid] = tsum;
  __syncthreads();
  for (int off = 1; off < 256; off <<= 1) {
    int v = (tid >= off) ? ls[tid - off] : 0;
    __syncthreads();
    ls[tid] += v;
    __syncthreads();
  }
  int excl = ls[tid] - tsum;
  if (base + 0 < N_NODES) row_start[base + 0] = excl;
  if (base + 1 < N_NODES) row_start[base + 1] = excl + c0;
  if (base + 2 < N_NODES) row_start[base + 2] = excl + c0 + c1;
  if (base + 3 < N_NODES) row_start[base + 3] = excl + c0 + c1 + c2;
  if (tid == 255) blk_sums[blockIdx.x] = ls[255];
}

__global__ __launch_bounds__(128) void k_scan_blk(int* __restrict__ blk_sums) {
  __shared__ int ls[128];
  const int tid = threadIdx.x;
  int v = (tid < NBLK_SCAN) ? blk_sums[tid] : 0;
  ls[tid] = v;
  __syncthreads();
  for (int off = 1; off < 128; off <<= 1) {
    int u = (tid >= off) ? ls[tid - off] : 0;
    __syncthreads();
    ls[tid] += u;
    __syncthreads();
  }
  if (tid < NBLK_SCAN) blk_sums[tid] = ls[tid] - v;
}

__global__ __launch_bounds__(256) void k_scan_add(int* __restrict__ row_start,
                                                  const int* __restrict__ blk_sums) {
  int i = blockIdx.x * 256 + threadIdx.x;
  if (i < N_NODES) row_start[i] += blk_sums[i / SCAN_CHUNK];
}

// ---------- scatter src ids into dst-sorted order ----------
__global__ __launch_bounds__(256) void k_scatter(const int* __restrict__ src,
                                                 const int* __restrict__ dst,
                                                 const int* __restrict__ row_start,
                                                 int* __restrict__ cursor,
                                                 int* __restrict__ sorted_src) {
  int e = blockIdx.x * 256 + threadIdx.x;
  if (e >= N_EDGES) return;
  int d = dst[e];
  int pos = row_start[d] + atomicAdd(&cursor[d], 1);
  sorted_src[pos] = src[e];
}

// ---------- layer 1 GEMM: h1 = x @ W1 ----------
// lane = row, 64 accumulators in VGPRs. W indices are threadIdx-independent
// -> uniform loads -> s_load into SGPRs (v_fma with SGPR operand). No LDS.
__global__ __launch_bounds__(256) void k_gemm1(const float* __restrict__ x,
                                               const float* __restrict__ W,
                                               float* __restrict__ h1) {
  int row = blockIdx.x * 256 + threadIdx.x;
  if (row >= N_NODES) row = N_NODES - 1;  // clamp: duplicate work, uniform control flow
  const float4* xr = (const float4*)(x + (size_t)row * DIM_IN);

  float acc[DIM_H];
#pragma unroll
  for (int j = 0; j < DIM_H; ++j) acc[j] = 0.f;

#pragma unroll 1
  for (int k4 = 0; k4 < DIM_IN / 4; ++k4) {
    float4 xv = xr[k4];
#pragma unroll
    for (int kk = 0; kk < 4; ++kk) {
      float xk = (kk == 0) ? xv.x : (kk == 1) ? xv.y : (kk == 2) ? xv.z : xv.w;
      const float* wrow = W + (size_t)(4 * k4 + kk) * DIM_H;  // wave-uniform
#pragma unroll
      for (int j = 0; j < DIM_H; ++j)
        acc[j] = fmaf(xk, wrow[j], acc[j]);
    }
  }

  float4* out = (float4*)(h1 + (size_t)row * DIM_H);  // 256B row stride: aligned
#pragma unroll
  for (int j4 = 0; j4 < DIM_H / 4; ++j4)
    out[j4] = make_float4(acc[4 * j4], acc[4 * j4 + 1], acc[4 * j4 + 2], acc[4 * j4 + 3]);
}

// ---------- agg1 gather: wave per node, lane = channel, CSR loop ----------
__global__ __launch_bounds__(256) void k_agg1_gather(const float* __restrict__ h1,
                                                     const float* __restrict__ dinv,
                                                     const float* __restrict__ b1,
                                                     const int* __restrict__ row_start,
                                                     const int* __restrict__ cnt,
                                                     const int* __restrict__ sorted_src,
                                                     float* __restrict__ agg1) {
  int n = blockIdx.x * 4 + (threadIdx.x >> 6);
  int j = threadIdx.x & 63;
  if (n >= N_NODES) return;
  float di = dinv[n];
  float acc = di * di * h1[(size_t)n * DIM_H + j] + b1[j];
  int start = row_start[n];
  int deg   = cnt[n];
  for (int k = 0; k < deg; ++k) {
    int s = sorted_src[start + k];
    float w = dinv[s] * di;
    acc = fmaf(w, h1[(size_t)s * DIM_H + j], acc);
  }
  agg1[(size_t)n * DIM_H + j] = acc;
}

// ---------- layer 2 GEMM, fused ReLU: h2 = relu(agg1) @ W2 ----------
// Same scalar-W pattern; K=64, 47 accumulators.
__global__ __launch_bounds__(256) void k_gemm2(const float* __restrict__ agg1,
                                               const float* __restrict__ W,
                                               float* __restrict__ h2) {
  int row = blockIdx.x * 256 + threadIdx.x;
  if (row >= N_NODES) row = N_NODES - 1;
  const float4* xr = (const float4*)(agg1 + (size_t)row * DIM_H);  // 256B stride: aligned

  float acc[DIM_C];
#pragma unroll
  for (int j = 0; j < DIM_C; ++j) acc[j] = 0.f;

#pragma unroll 1
  for (int k4 = 0; k4 < DIM_H / 4; ++k4) {
    float4 xv = xr[k4];
    xv.x = fmaxf(xv.x, 0.f); xv.y = fmaxf(xv.y, 0.f);
    xv.z = fmaxf(xv.z, 0.f); xv.w = fmaxf(xv.w, 0.f);
#pragma unroll
    for (int kk = 0; kk < 4; ++kk) {
      float xk = (kk == 0) ? xv.x : (kk == 1) ? xv.y : (kk == 2) ? xv.z : xv.w;
      const float* wrow = W + (size_t)(4 * k4 + kk) * DIM_C;  // wave-uniform
#pragma unroll
      for (int j = 0; j < DIM_C; ++j)
        acc[j] = fmaf(xk, wrow[j], acc[j]);
    }
  }

  float* out = h2 + (size_t)row * DIM_C;  // 188B stride: scalar stores (alignment)
#pragma unroll
  for (int j = 0; j < DIM_C; ++j) out[j] = acc[j];
}

// ---------- agg2 gather + fused log_softmax: wave per node ----------
__global__ __launch_bounds__(256) void k_agg2_gather(const float* __restrict__ h2,
                                                     const float* __restrict__ dinv,
                                                     const float* __restrict__ b2,
                                                     const int* __restrict__ row_start,
                                                     const int* __restrict__ cnt,
                                                     const int* __restrict__ sorted_src,
                                                     float* __restrict__ out) {
  int n = blockIdx.x * 4 + (threadIdx.x >> 6);
  int j = threadIdx.x & 63;
  if (n >= N_NODES) return;
  int jj = (j < DIM_C) ? j : (DIM_C - 1);  // clamp; lanes >=47 masked at the end
  float di = dinv[n];
  float acc = di * di * h2[(size_t)n * DIM_C + jj] + b2[jj];
  int start = row_start[n];
  int deg   = cnt[n];
  for (int k = 0; k < deg; ++k) {
    int s = sorted_src[start + k];
    float w = dinv[s] * di;
    acc = fmaf(w, h2[(size_t)s * DIM_C + jj], acc);
  }
  float v = (j < DIM_C) ? acc : -INFINITY;
  float m = v;
  for (int o = 32; o; o >>= 1) m = fmaxf(m, __shfl_xor(m, o));
  float ex = (j < DIM_C) ? __expf(v - m) : 0.0f;
  float s = ex;
  for (int o = 32; o; o >>= 1) s += __shfl_xor(s, o);
  if (j < DIM_C) out[(size_t)n * DIM_C + j] = v - m - __logf(s);
}

extern "C" void kernel_launch(void* const* d_in, const int* in_sizes, int n_in,
                              void* d_out, int out_size, void* d_ws, size_t ws_size,
                              hipStream_t stream) {
  const float* x  = (const float*)d_in[0];
  const float* W1 = (const float*)d_in[1];
  const float* b1 = (const float*)d_in[2];
  const float* W2 = (const float*)d_in[3];
  const float* b2 = (const float*)d_in[4];
  const int*   ei = (const int*)d_in[5];
  const int* src = ei;
  const int* dst = ei + N_EDGES;
  float* out = (float*)d_out;

  float* ws   = (float*)d_ws;
  float* dinv = ws;                                   // N
  float* h1   = dinv + N_NODES;                       // N*64 (reused for h2)
  float* agg1 = h1 + (size_t)N_NODES * DIM_H;         // N*64
  float* h2   = h1;                                   // alias: h1 dead after agg1
  int* ibuf       = (int*)(agg1 + (size_t)N_NODES * DIM_H);
  int* cnt        = ibuf;                             // N
  int* cursor     = cnt + N_NODES;                    // N
  int* row_start  = cursor + N_NODES;                 // N
  int* blk_sums   = row_start + N_NODES;              // 128
  int* sorted_src = blk_sums + 128;                   // E

  const int nblk_n  = (N_NODES + 255) / 256;
  const int nblk_e  = (N_EDGES + 255) / 256;
  const int nblk_nw = (N_NODES + 3) / 4;              // wave-per-node gathers
  const int nblk_r  = (N_NODES + 255) / 256;          // lane-per-row GEMMs

  // CSR build
  k_zero<<<nblk_n, 256, 0, stream>>>(cnt, cursor);
  k_hist<<<nblk_e, 256, 0, stream>>>(dst, cnt);
  k_dinv<<<nblk_n, 256, 0, stream>>>(cnt, dinv);
  k_scan_partial<<<NBLK_SCAN, 256, 0, stream>>>(cnt, row_start, blk_sums);
  k_scan_blk<<<1, 128, 0, stream>>>(blk_sums);
  k_scan_add<<<nblk_n, 256, 0, stream>>>(row_start, blk_sums);
  k_scatter<<<nblk_e, 256, 0, stream>>>(src, dst, row_start, cursor, sorted_src);

  // layer 1
  k_gemm1<<<nblk_r, 256, 0, stream>>>(x, W1, h1);
  k_agg1_gather<<<nblk_nw, 256, 0, stream>>>(h1, dinv, b1, row_start, cnt, sorted_src, agg1);

  // layer 2 (+ fused log_softmax)
  k_gemm2<<<nblk_r, 256, 0, stream>>>(agg1, W2, h2);
  k_agg2_gather<<<nblk_nw, 256, 0, stream>>>(h2, dinv, b2, row_start, cnt, sorted_src, out);
}

// Round 5
// 452.060 us; speedup vs baseline: 2.7345x; 1.3455x over previous
//
#include <hip/hip_runtime.h>
#include <math.h>

#define N_NODES 100000
#define N_EDGES 1600000
#define DIM_IN  256
#define DIM_H   64
#define DIM_C   47
#define DIM_CP  48                            // padded h2 row stride (192B aligned)
#define SCAN_CHUNK 1024                       // elems per scan block (256 thr x 4)
#define NBLK_SCAN ((N_NODES + SCAN_CHUNK - 1) / SCAN_CHUNK)   // 98

// ---------- zero int buffers (cnt, cursor) ----------
__global__ __launch_bounds__(256) void k_zero(int* __restrict__ cnt,
                                              int* __restrict__ cursor) {
  int i = blockIdx.x * 256 + threadIdx.x;
  if (i < N_NODES) { cnt[i] = 0; cursor[i] = 0; }
}

// ---------- in-degree histogram ----------
__global__ __launch_bounds__(256) void k_hist(const int* __restrict__ dst,
                                              int* __restrict__ cnt) {
  int e = blockIdx.x * 256 + threadIdx.x;
  if (e < N_EDGES) atomicAdd(&cnt[dst[e]], 1);
}

// ---------- dinv = rsqrt(deg+1)  (self-loop) ----------
__global__ __launch_bounds__(256) void k_dinv(const int* __restrict__ cnt,
                                              float* __restrict__ dinv) {
  int i = blockIdx.x * 256 + threadIdx.x;
  if (i < N_NODES) dinv[i] = rsqrtf((float)cnt[i] + 1.0f);
}

// ---------- exclusive scan of cnt -> row_start (3 kernels) ----------
__global__ __launch_bounds__(256) void k_scan_partial(const int* __restrict__ cnt,
                                                      int* __restrict__ row_start,
                                                      int* __restrict__ blk_sums) {
  __shared__ int ls[256];
  const int tid  = threadIdx.x;
  const int base = blockIdx.x * SCAN_CHUNK + tid * 4;
  int c0 = (base + 0 < N_NODES) ? cnt[base + 0] : 0;
  int c1 = (base + 1 < N_NODES) ? cnt[base + 1] : 0;
  int c2 = (base + 2 < N_NODES) ? cnt[base + 2] : 0;
  int c3 = (base + 3 < N_NODES) ? cnt[base + 3] : 0;
  int tsum = c0 + c1 + c2 + c3;
  ls[tid] = tsum;
  __syncthreads();
  for (int off = 1; off < 256; off <<= 1) {
    int v = (tid >= off) ? ls[tid - off] : 0;
    __syncthreads();
    ls[tid] += v;
    __syncthreads();
  }
  int excl = ls[tid] - tsum;
  if (base + 0 < N_NODES) row_start[base + 0] = excl;
  if (base + 1 < N_NODES) row_start[base + 1] = excl + c0;
  if (base + 2 < N_NODES) row_start[base + 2] = excl + c0 + c1;
  if (base + 3 < N_NODES) row_start[base + 3] = excl + c0 + c1 + c2;
  if (tid == 255) blk_sums[blockIdx.x] = ls[255];
}

__global__ __launch_bounds__(128) void k_scan_blk(int* __restrict__ blk_sums) {
  __shared__ int ls[128];
  const int tid = threadIdx.x;
  int v = (tid < NBLK_SCAN) ? blk_sums[tid] : 0;
  ls[tid] = v;
  __syncthreads();
  for (int off = 1; off < 128; off <<= 1) {
    int u = (tid >= off) ? ls[tid - off] : 0;
    __syncthreads();
    ls[tid] += u;
    __syncthreads();
  }
  if (tid < NBLK_SCAN) blk_sums[tid] = ls[tid] - v;
}

__global__ __launch_bounds__(256) void k_scan_add(int* __restrict__ row_start,
                                                  const int* __restrict__ blk_sums) {
  int i = blockIdx.x * 256 + threadIdx.x;
  if (i < N_NODES) row_start[i] += blk_sums[i / SCAN_CHUNK];
}

// ---------- scatter src ids into dst-sorted order ----------
__global__ __launch_bounds__(256) void k_scatter(const int* __restrict__ src,
                                                 const int* __restrict__ dst,
                                                 const int* __restrict__ row_start,
                                                 int* __restrict__ cursor,
                                                 int* __restrict__ sorted_src) {
  int e = blockIdx.x * 256 + threadIdx.x;
  if (e >= N_EDGES) return;
  int d = dst[e];
  int pos = row_start[d] + atomicAdd(&cursor[d], 1);
  sorted_src[pos] = src[e];
}

// ---------- layer 1 GEMM + dinv pre-scale: h1s = dinv[n] * (x @ W1) ----------
// lane = row, 64 accumulators in VGPRs, W via wave-uniform scalar loads, no LDS.
__global__ __launch_bounds__(256) void k_gemm1(const float* __restrict__ x,
                                               const float* __restrict__ W,
                                               const float* __restrict__ dinv,
                                               float* __restrict__ h1s) {
  int row = blockIdx.x * 256 + threadIdx.x;
  if (row >= N_NODES) row = N_NODES - 1;  // clamp: duplicate work, uniform control flow
  const float4* xr = (const float4*)(x + (size_t)row * DIM_IN);

  float acc[DIM_H];
#pragma unroll
  for (int j = 0; j < DIM_H; ++j) acc[j] = 0.f;

#pragma unroll 1
  for (int k4 = 0; k4 < DIM_IN / 4; ++k4) {
    float4 xv = xr[k4];
#pragma unroll
    for (int kk = 0; kk < 4; ++kk) {
      float xk = (kk == 0) ? xv.x : (kk == 1) ? xv.y : (kk == 2) ? xv.z : xv.w;
      const float* wrow = W + (size_t)(4 * k4 + kk) * DIM_H;  // wave-uniform
#pragma unroll
      for (int j = 0; j < DIM_H; ++j)
        acc[j] = fmaf(xk, wrow[j], acc[j]);
    }
  }

  float di = dinv[row];
  float4* out = (float4*)(h1s + (size_t)row * DIM_H);
#pragma unroll
  for (int j4 = 0; j4 < DIM_H / 4; ++j4)
    out[j4] = make_float4(di * acc[4 * j4], di * acc[4 * j4 + 1],
                          di * acc[4 * j4 + 2], di * acc[4 * j4 + 3]);
}

// ---------- agg1 gather: wave per node, lane = channel, 4-way unrolled CSR loop ----------
// agg1[n][j] = dinv[n] * (h1s[n][j] + sum_s h1s[s][j]) + b1[j]
__global__ __launch_bounds__(256) void k_agg1_gather(const float* __restrict__ h1s,
                                                     const float* __restrict__ dinv,
                                                     const float* __restrict__ b1,
                                                     const int* __restrict__ row_start,
                                                     const int* __restrict__ cnt,
                                                     const int* __restrict__ sorted_src,
                                                     float* __restrict__ agg1) {
  int n = blockIdx.x * 4 + (threadIdx.x >> 6);
  int j = threadIdx.x & 63;
  if (n >= N_NODES) return;
  int start = row_start[n];
  int deg   = cnt[n];
  float acc0 = h1s[(size_t)n * DIM_H + j];  // self term
  float acc1 = 0.f, acc2 = 0.f, acc3 = 0.f;
  int k = 0;
  for (; k + 4 <= deg; k += 4) {
    int s0 = sorted_src[start + k + 0];
    int s1 = sorted_src[start + k + 1];
    int s2 = sorted_src[start + k + 2];
    int s3 = sorted_src[start + k + 3];
    acc0 += h1s[(size_t)s0 * DIM_H + j];
    acc1 += h1s[(size_t)s1 * DIM_H + j];
    acc2 += h1s[(size_t)s2 * DIM_H + j];
    acc3 += h1s[(size_t)s3 * DIM_H + j];
  }
  for (; k < deg; ++k)
    acc0 += h1s[(size_t)sorted_src[start + k] * DIM_H + j];
  float di = dinv[n];
  agg1[(size_t)n * DIM_H + j] = di * ((acc0 + acc1) + (acc2 + acc3)) + b1[j];
}

// ---------- layer 2 GEMM + ReLU + dinv pre-scale: h2p = dinv[n]*(relu(agg1) @ W2) ----------
__global__ __launch_bounds__(256) void k_gemm2(const float* __restrict__ agg1,
                                               const float* __restrict__ W,
                                               const float* __restrict__ dinv,
                                               float* __restrict__ h2p) {
  int row = blockIdx.x * 256 + threadIdx.x;
  if (row >= N_NODES) row = N_NODES - 1;
  const float4* xr = (const float4*)(agg1 + (size_t)row * DIM_H);

  float acc[DIM_C];
#pragma unroll
  for (int j = 0; j < DIM_C; ++j) acc[j] = 0.f;

#pragma unroll 1
  for (int k4 = 0; k4 < DIM_H / 4; ++k4) {
    float4 xv = xr[k4];
    xv.x = fmaxf(xv.x, 0.f); xv.y = fmaxf(xv.y, 0.f);
    xv.z = fmaxf(xv.z, 0.f); xv.w = fmaxf(xv.w, 0.f);
#pragma unroll
    for (int kk = 0; kk < 4; ++kk) {
      float xk = (kk == 0) ? xv.x : (kk == 1) ? xv.y : (kk == 2) ? xv.z : xv.w;
      const float* wrow = W + (size_t)(4 * k4 + kk) * DIM_C;  // wave-uniform
#pragma unroll
      for (int j = 0; j < DIM_C; ++j)
        acc[j] = fmaf(xk, wrow[j], acc[j]);
    }
  }

  float di = dinv[row];
  float* out = h2p + (size_t)row * DIM_CP;
#pragma unroll
  for (int j = 0; j < DIM_C; ++j) out[j] = di * acc[j];
  out[DIM_C] = 0.f;  // init pad (lane 47 reads it)
}

// ---------- agg2 gather + fused log_softmax: wave per node, 4-way unrolled ----------
__global__ __launch_bounds__(256) void k_agg2_gather(const float* __restrict__ h2p,
                                                     const float* __restrict__ dinv,
                                                     const float* __restrict__ b2,
                                                     const int* __restrict__ row_start,
                                                     const int* __restrict__ cnt,
                                                     const int* __restrict__ sorted_src,
                                                     float* __restrict__ out) {
  int n = blockIdx.x * 4 + (threadIdx.x >> 6);
  int j = threadIdx.x & 63;
  if (n >= N_NODES) return;
  int jj = (j < DIM_C) ? j : DIM_C;  // lanes >=47 read the zero pad
  int start = row_start[n];
  int deg   = cnt[n];
  float acc0 = h2p[(size_t)n * DIM_CP + jj];  // self term
  float acc1 = 0.f, acc2 = 0.f, acc3 = 0.f;
  int k = 0;
  for (; k + 4 <= deg; k += 4) {
    int s0 = sorted_src[start + k + 0];
    int s1 = sorted_src[start + k + 1];
    int s2 = sorted_src[start + k + 2];
    int s3 = sorted_src[start + k + 3];
    acc0 += h2p[(size_t)s0 * DIM_CP + jj];
    acc1 += h2p[(size_t)s1 * DIM_CP + jj];
    acc2 += h2p[(size_t)s2 * DIM_CP + jj];
    acc3 += h2p[(size_t)s3 * DIM_CP + jj];
  }
  for (; k < deg; ++k)
    acc0 += h2p[(size_t)sorted_src[start + k] * DIM_CP + jj];
  float di = dinv[n];
  float acc = di * ((acc0 + acc1) + (acc2 + acc3)) + ((j < DIM_C) ? b2[jj] : 0.f);

  // fused log_softmax over the 47 classes
  float v = (j < DIM_C) ? acc : -INFINITY;
  float m = v;
  for (int o = 32; o; o >>= 1) m = fmaxf(m, __shfl_xor(m, o));
  float ex = (j < DIM_C) ? __expf(v - m) : 0.0f;
  float s = ex;
  for (int o = 32; o; o >>= 1) s += __shfl_xor(s, o);
  if (j < DIM_C) out[(size_t)n * DIM_C + j] = v - m - __logf(s);
}

extern "C" void kernel_launch(void* const* d_in, const int* in_sizes, int n_in,
                              void* d_out, int out_size, void* d_ws, size_t ws_size,
                              hipStream_t stream) {
  const float* x  = (const float*)d_in[0];
  const float* W1 = (const float*)d_in[1];
  const float* b1 = (const float*)d_in[2];
  const float* W2 = (const float*)d_in[3];
  const float* b2 = (const float*)d_in[4];
  const int*   ei = (const int*)d_in[5];
  const int* src = ei;
  const int* dst = ei + N_EDGES;
  float* out = (float*)d_out;

  float* ws   = (float*)d_ws;
  float* dinv = ws;                                   // N
  float* h1s  = dinv + N_NODES;                       // N*64 (reused for h2p, N*48)
  float* agg1 = h1s + (size_t)N_NODES * DIM_H;        // N*64
  float* h2p  = h1s;                                  // alias: h1s dead after agg1_gather
  int* ibuf       = (int*)(agg1 + (size_t)N_NODES * DIM_H);
  int* cnt        = ibuf;                             // N
  int* cursor     = cnt + N_NODES;                    // N
  int* row_start  = cursor + N_NODES;                 // N
  int* blk_sums   = row_start + N_NODES;              // 128
  int* sorted_src = blk_sums + 128;                   // E

  const int nblk_n  = (N_NODES + 255) / 256;
  const int nblk_e  = (N_EDGES + 255) / 256;
  const int nblk_nw = (N_NODES + 3) / 4;              // wave-per-node gathers
  const int nblk_r  = (N_NODES + 255) / 256;          // lane-per-row GEMMs

  // CSR build
  k_zero<<<nblk_n, 256, 0, stream>>>(cnt, cursor);
  k_hist<<<nblk_e, 256, 0, stream>>>(dst, cnt);
  k_dinv<<<nblk_n, 256, 0, stream>>>(cnt, dinv);
  k_scan_partial<<<NBLK_SCAN, 256, 0, stream>>>(cnt, row_start, blk_sums);
  k_scan_blk<<<1, 128, 0, stream>>>(blk_sums);
  k_scan_add<<<nblk_n, 256, 0, stream>>>(row_start, blk_sums);
  k_scatter<<<nblk_e, 256, 0, stream>>>(src, dst, row_start, cursor, sorted_src);

  // layer 1
  k_gemm1<<<nblk_r, 256, 0, stream>>>(x, W1, dinv, h1s);
  k_agg1_gather<<<nblk_nw, 256, 0, stream>>>(h1s, dinv, b1, row_start, cnt, sorted_src, agg1);

  // layer 2 (+ fused log_softmax)
  k_gemm2<<<nblk_r, 256, 0, stream>>>(agg1, W2, dinv, h2p);
  k_agg2_gather<<<nblk_nw, 256, 0, stream>>>(h2p, dinv, b2, row_start, cnt, sorted_src, out);
}